// Round 6
// baseline (529.604 us; speedup 1.0000x reference)
//
#include <hip/hip_runtime.h>

#define S_LEN 512
#define D_DIM 512
#define BATCH 32
#define M_ROWS (BATCH * S_LEN)   // 16384
#define NLAYER 3

typedef unsigned short ushort_t;
typedef __bf16 bf16_t;
typedef bf16_t bf16x8 __attribute__((ext_vector_type(8)));
typedef unsigned short u16x8 __attribute__((ext_vector_type(8)));
typedef float f32x4 __attribute__((ext_vector_type(4)));

typedef const __attribute__((address_space(1))) unsigned int* gptr_t;
typedef __attribute__((address_space(3))) unsigned int* lptr_t;

__device__ __forceinline__ ushort_t f2bf(float f) {
  unsigned u = __float_as_uint(f);
  unsigned r = (u + 0x7fffu + ((u >> 16) & 1u)) >> 16;   // RNE
  return (ushort_t)r;
}

__device__ __forceinline__ float4 f4fma(float w, float4 u, float4 a) {
  a.x = fmaf(w, u.x, a.x); a.y = fmaf(w, u.y, a.y);
  a.z = fmaf(w, u.z, a.z); a.w = fmaf(w, u.w, a.w);
  return a;
}

// ---------------------------------------------------------------------------
// Weight prep: w[k][n] fp32 -> wt[n][k] bf16 (B^T layout for the GEMM)
// ---------------------------------------------------------------------------
__global__ __launch_bounds__(256)
void wprep_kernel(const float* __restrict__ fw1, const float* __restrict__ fw2,
                  const float* __restrict__ bw1, const float* __restrict__ bw2,
                  ushort_t* __restrict__ wt1, ushort_t* __restrict__ wt2) {
  int z = blockIdx.z;
  int l = z >> 2, m = z & 3;
  const float* bases[4] = {fw1, fw2, bw1, bw2};
  const float* src = bases[m] + (size_t)l * D_DIM * D_DIM;
  int streamIdx = m >> 1;
  int which = m & 1;
  ushort_t* dst = (which ? wt2 : wt1) + ((size_t)streamIdx * NLAYER + l) * D_DIM * D_DIM;

  __shared__ float tile[32][33];
  int n0 = blockIdx.x * 32, k0 = blockIdx.y * 32;
  int tx = threadIdx.x, ty = threadIdx.y;
#pragma unroll
  for (int i = 0; i < 32; i += 8)
    tile[ty + i][tx] = src[(size_t)(k0 + ty + i) * D_DIM + n0 + tx];
  __syncthreads();
#pragma unroll
  for (int i = 0; i < 32; i += 8)
    dst[(size_t)(n0 + ty + i) * D_DIM + k0 + tx] = f2bf(tile[tx][ty + i]);
}

// ---------------------------------------------------------------------------
// Fused window-conv + LayerNorm (R5 version, measured-neutral vs R1).
// grid (M_ROWS/16, 2), block 256, 4 rows per wave.
// ---------------------------------------------------------------------------
__global__ __launch_bounds__(256, 4)
void conv_ln_kernel(const float* __restrict__ srcF, int strideF,
                    const float* __restrict__ srcB, int strideB,
                    const float* __restrict__ padLo, const float* __restrict__ padHi,
                    const float* __restrict__ wF, const float* __restrict__ wB,
                    const float* __restrict__ gF, const float* __restrict__ beF,
                    const float* __restrict__ gB, const float* __restrict__ beB,
                    ushort_t* __restrict__ yln) {
  int z = blockIdx.y;
  int tid = threadIdx.x;
  int lane = tid & 63;
  int wid = tid >> 6;
  int row0 = (blockIdx.x * 4 + wid) * 4;
  int t0 = row0 & (S_LEN - 1);
  const float* src = z ? srcB : srcF;
  int stride = z ? strideB : strideF;
  const float* wv = z ? wB : wF;
  const float* gv = z ? gB : gF;
  const float* bv = z ? beB : beF;
  int toff = z ? 0 : -3;
  int c0 = lane * 4, c1 = 256 + lane * 4;

  float w0 = wv[0], w1 = wv[1], w2 = wv[2], w3 = wv[3];

  float4 u0[7], u1[7];
#pragma unroll
  for (int q = 0; q < 7; ++q) {
    int tt = t0 + toff + q;
    const float* rp;
    if (tt < 0)            rp = padLo + (size_t)(tt + 3) * D_DIM;
    else if (tt >= S_LEN)  rp = padHi + (size_t)(tt - S_LEN) * D_DIM;
    else                   rp = src + (size_t)(row0 + toff + q) * stride;
    u0[q] = *(const float4*)(rp + c0);
    u1[q] = *(const float4*)(rp + c1);
  }

  float4 g0 = *(const float4*)(gv + c0), g1 = *(const float4*)(gv + c1);
  float4 b0 = *(const float4*)(bv + c0), b1 = *(const float4*)(bv + c1);

  float4 y0[4], y1[4];
#pragma unroll
  for (int j = 0; j < 4; ++j) {
    float4 a = make_float4(0.f, 0.f, 0.f, 0.f);
    a = f4fma(w0, u0[j], a); a = f4fma(w1, u0[j + 1], a);
    a = f4fma(w2, u0[j + 2], a); a = f4fma(w3, u0[j + 3], a);
    y0[j] = a;
    float4 c = make_float4(0.f, 0.f, 0.f, 0.f);
    c = f4fma(w0, u1[j], c); c = f4fma(w1, u1[j + 1], c);
    c = f4fma(w2, u1[j + 2], c); c = f4fma(w3, u1[j + 3], c);
    y1[j] = c;
  }

  float s[4], s2[4];
#pragma unroll
  for (int j = 0; j < 4; ++j) {
    float4 a = y0[j], c = y1[j];
    s[j] = a.x + a.y + a.z + a.w + c.x + c.y + c.z + c.w;
    float t = a.x * a.x;
    t = fmaf(a.y, a.y, t); t = fmaf(a.z, a.z, t); t = fmaf(a.w, a.w, t);
    t = fmaf(c.x, c.x, t); t = fmaf(c.y, c.y, t); t = fmaf(c.z, c.z, t);
    t = fmaf(c.w, c.w, t);
    s2[j] = t;
  }

#pragma unroll
  for (int o = 32; o; o >>= 1) {
#pragma unroll
    for (int j = 0; j < 4; ++j) {
      s[j]  += __shfl_xor(s[j],  o);
      s2[j] += __shfl_xor(s2[j], o);
    }
  }

  size_t base = ((size_t)z * M_ROWS + row0) * D_DIM;
#pragma unroll
  for (int j = 0; j < 4; ++j) {
    float mean = s[j] * (1.0f / 512.0f);
    float qv = fmaf(-512.0f * mean, mean, s2[j]);
    qv = fmaxf(qv, 0.0f);
    float sd = sqrtf(qv * (1.0f / 511.0f));
    float inv = 1.0f / (sd + 1e-6f);
    ushort_t p0[4], p1[4];
    p0[0] = f2bf(g0.x * ((y0[j].x - mean) * inv) + b0.x);
    p0[1] = f2bf(g0.y * ((y0[j].y - mean) * inv) + b0.y);
    p0[2] = f2bf(g0.z * ((y0[j].z - mean) * inv) + b0.z);
    p0[3] = f2bf(g0.w * ((y0[j].w - mean) * inv) + b0.w);
    p1[0] = f2bf(g1.x * ((y1[j].x - mean) * inv) + b1.x);
    p1[1] = f2bf(g1.y * ((y1[j].y - mean) * inv) + b1.y);
    p1[2] = f2bf(g1.z * ((y1[j].z - mean) * inv) + b1.z);
    p1[3] = f2bf(g1.w * ((y1[j].w - mean) * inv) + b1.w);
    *(uint2*)(yln + base + (size_t)j * D_DIM + c0) = *(uint2*)p0;
    *(uint2*)(yln + base + (size_t)j * D_DIM + c1) = *(uint2*)p1;
  }
}

// ---------------------------------------------------------------------------
// 128x512-tile (full-N) 8-wave bf16 MFMA GEMM, BK=32, 16 K-tiles.
// Grid 256 (1 block/CU), 512 threads, wave grid 2M x 4N (wave = 64r x 128c).
// A staged ONCE from HBM (8 KB/tile); B (512 KB/stream) L2-resident,
// staged in two row-sets matching phase needs (set s = rows with bit6==s).
// Swizzle: 4 chunks/row -> 2-row fold  chunk' = chunk ^ ((row>>1)&3)
//   (bijective per row; spreads 16-row column reads over 8 bank-slots = 2-way).
// Schedule per tile g (2 phases):
//   ph0: read A+Bset0 frags; stage B1(g+1); barrier;lgkm0; 16 MFMA; vmcnt(M);bar
//   ph1: read Bset1 frags;  stage A,B0(g+2); barrier;lgkm0; 16 MFMA; vmcnt(C);bar
//   steady vmcnt = 5 (in-flight 5-7, never drained); tail: g14-end=2, g15-mid=0.
// ---------------------------------------------------------------------------
#define SB() __builtin_amdgcn_sched_barrier(0)

#define GPHASE_PRE()                                        \
  SB();                                                     \
  __builtin_amdgcn_s_barrier();                             \
  asm volatile("s_waitcnt lgkmcnt(0)" ::: "memory");        \
  SB();                                                     \
  __builtin_amdgcn_s_setprio(1);

#define GPHASE_POST(VM)                                     \
  __builtin_amdgcn_s_setprio(0);                            \
  SB();                                                     \
  asm volatile("s_waitcnt vmcnt(" #VM ")" ::: "memory");    \
  SB();                                                     \
  __builtin_amdgcn_s_barrier();

#define READ_AF()                                                         \
  _Pragma("unroll")                                                       \
  for (int m_ = 0; m_ < 4; ++m_) {                                        \
    int row_ = wr * 64 + m_ * 16 + lm;                                    \
    int idx_ = row_ * 32 + ((lq ^ ((row_ >> 1) & 3)) * 8);                \
    union { u16x8 u; bf16x8 b; } t_;                                      \
    t_.u = *(const u16x8*)&pa[idx_];                                      \
    aF[m_] = t_.b;                                                        \
  }

#define READ_BF(PH)                                                       \
  _Pragma("unroll")                                                       \
  for (int n_ = 0; n_ < 4; ++n_) {                                        \
    int row_ = wc * 128 + ((PH) * 4 + n_) * 16 + lm;                      \
    int idx_ = row_ * 32 + ((lq ^ ((row_ >> 1) & 3)) * 8);                \
    union { u16x8 u; bf16x8 b; } t_;                                      \
    t_.u = *(const u16x8*)&pb[idx_];                                      \
    bF[n_] = t_.b;                                                        \
  }

#define MFMA_PH(PH)                                                       \
  _Pragma("unroll")                                                       \
  for (int m_ = 0; m_ < 4; ++m_)                                          \
    _Pragma("unroll")                                                     \
    for (int n_ = 0; n_ < 4; ++n_)                                        \
      acc[m_][(PH) * 4 + n_] =                                            \
          __builtin_amdgcn_mfma_f32_16x16x32_bf16(                        \
              aF[m_], bF[n_], acc[m_][(PH) * 4 + n_], 0, 0, 0);

template <int EPI>
__global__ __launch_bounds__(512, 2)
void gemmN_kernel(const ushort_t* __restrict__ A,
                  const ushort_t* __restrict__ Bt_f, const ushort_t* __restrict__ Bt_b,
                  const float* __restrict__ bias_f, const float* __restrict__ bias_b,
                  ushort_t* __restrict__ Hout,       // (EPI==1)
                  float* __restrict__ Cout,          // (EPI==2)
                  const float* __restrict__ srcF, const float* __restrict__ srcB,
                  int srcStride,
                  const float* __restrict__ padLo, const float* __restrict__ padHi,
                  const float* __restrict__ wF, const float* __restrict__ wB) {
  const int K = 512;
  // XCD-aware bijective swizzle (256 blocks / 8 XCDs = 32 each)
  int bid = blockIdx.x;
  int G = (bid & 7) * 32 + (bid >> 3);
  int z = G >> 7;
  int mblk = G & 127;
  int row0 = mblk * 128;

  const ushort_t* Ab = A + (size_t)z * M_ROWS * K + (size_t)row0 * K;
  const ushort_t* Bb = z ? Bt_b : Bt_f;

  __shared__ __attribute__((aligned(16))) ushort_t As[2][128 * 32];  //  2x8 KB
  __shared__ __attribute__((aligned(16))) ushort_t Bs[2][512 * 32];  // 2x32 KB

  int tid = threadIdx.x, lane = tid & 63, wave = tid >> 6;
  int wr = wave >> 2, wc = wave & 3;          // 2M x 4N wave grid
  int lm = lane & 15, lq = lane >> 4;

  // stage A-tile [128][32] for K-tile g : 1 chunk/thread
  auto STAGE_A = [&](int g, ushort_t* dst) {
    int r = tid >> 2, c = tid & 3;
    int cs = c ^ ((r >> 1) & 3);
    __builtin_amdgcn_global_load_lds(
        (gptr_t)(const void*)(Ab + (size_t)r * 512 + g * 32 + cs * 8),
        (lptr_t)(void*)(dst + tid * 8), 16, 0, 0);
  };
  // stage B row-set s (rows with bit6==s) of K-tile g : 2 chunks/thread
  auto STAGE_B = [&](int g, ushort_t* dst, int s) {
#pragma unroll
    for (int u = 0; u < 2; ++u) {
      int i = (u * 512 + tid) >> 2, c = tid & 3;
      int r = (i & 63) + ((i >> 6) << 7) + s * 64;
      int cs = c ^ ((r >> 1) & 3);
      __builtin_amdgcn_global_load_lds(
          (gptr_t)(const void*)(Bb + (size_t)r * 512 + g * 32 + cs * 8),
          (lptr_t)(void*)(dst + r * 32 + c * 8), 16, 0, 0);
    }
  };

  f32x4 acc[4][8] = {};
  bf16x8 aF[4], bF[4];

  // ---- prologue: t0 all (5) + A,B0(t1) (3) = 8 issues; wait t0 (vmcnt 3)
  STAGE_A(0, &As[0][0]);
  STAGE_B(0, &Bs[0][0], 0);
  STAGE_B(0, &Bs[0][0], 1);
  STAGE_A(1, &As[1][0]);
  STAGE_B(1, &Bs[1][0], 0);
  asm volatile("s_waitcnt vmcnt(3)" ::: "memory");
  SB();
  __builtin_amdgcn_s_barrier();

#pragma unroll
  for (int g = 0; g < 16; ++g) {
    const ushort_t* pa = &As[g & 1][0];
    const ushort_t* pb = &Bs[g & 1][0];
    ushort_t* na = &As[(g & 1) ^ 1][0];
    ushort_t* nb = &Bs[(g & 1) ^ 1][0];

    // ---- phase 0: read A + B-set0 frags; stage B1(g+1) -> other buf
    READ_AF()
    READ_BF(0)
    if (g + 1 < 16) STAGE_B(g + 1, nb, 1);
    GPHASE_PRE()
    MFMA_PH(0)
    if (g < 15) { GPHASE_POST(5) } else { GPHASE_POST(0) }   // B-set1(g) visible

    // ---- phase 1: read B-set1 frags; stage A,B0(g+2) -> current buf
    READ_BF(1)
    if (g + 2 < 16) { STAGE_A(g + 2, (ushort_t*)pa); STAGE_B(g + 2, (ushort_t*)pb, 0); }
    GPHASE_PRE()
    MFMA_PH(1)
    if (g < 14) { GPHASE_POST(5) }                           // A,B0(g+1) visible
    else if (g == 14) { GPHASE_POST(2) }
    else {
      __builtin_amdgcn_s_setprio(0);
      SB();
      __builtin_amdgcn_s_barrier();
    }
  }

  // ---- epilogue. C/D layout: col = lane&15 (lm), row = lq*4 + reg
  const float* bias = z ? bias_b : bias_f;
  if (EPI == 1) {
    ushort_t* Hb = Hout + (size_t)z * M_ROWS * 512;
#pragma unroll
    for (int mf = 0; mf < 4; ++mf) {
      int mbase = row0 + wr * 64 + mf * 16 + lq * 4;
#pragma unroll
      for (int nf = 0; nf < 8; ++nf) {
        int n = wc * 128 + nf * 16 + lm;
        float bvn = bias[n];
#pragma unroll
        for (int r = 0; r < 4; ++r) {
          float v = fmaxf(acc[mf][nf][r] + bvn, 0.0f);
          Hb[(size_t)(mbase + r) * 512 + n] = f2bf(v);
        }
      }
    }
  } else {
    const float* src = z ? srcB : srcF;
    const float* wv = z ? wB : wF;
    int toff = z ? 0 : -3;
    float w0 = wv[0], w1 = wv[1], w2 = wv[2], w3 = wv[3];
    float* Cb = Cout + (size_t)z * 512;
#pragma unroll
    for (int mf = 0; mf < 4; ++mf) {
      int mbase = row0 + wr * 64 + mf * 16 + lq * 4;
      int t0 = mbase & (S_LEN - 1);
      int rb = mbase - t0;
      const float* rp[7];
#pragma unroll
      for (int q = 0; q < 7; ++q) {
        int tt = t0 + toff + q;
        rp[q] = (tt < 0)       ? padLo + (size_t)(tt + 3) * D_DIM
              : (tt >= S_LEN)  ? padHi + (size_t)(tt - S_LEN) * D_DIM
                               : src + (size_t)(rb + tt) * srcStride;
      }
#pragma unroll
      for (int nf = 0; nf < 8; ++nf) {
        int n = wc * 128 + nf * 16 + lm;
        float v[7];
#pragma unroll
        for (int q = 0; q < 7; ++q) v[q] = rp[q][n];
        float bvn = bias[n];
#pragma unroll
        for (int r = 0; r < 4; ++r) {
          float y = w0 * v[r] + w1 * v[r + 1] + w2 * v[r + 2] + w3 * v[r + 3];
          Cb[(size_t)(mbase + r) * 1024 + n] = acc[mf][nf][r] + bvn + y;
        }
      }
    }
  }
}

// ---------------------------------------------------------------------------
extern "C" void kernel_launch(void* const* d_in, const int* in_sizes, int n_in,
                              void* d_out, int out_size, void* d_ws, size_t ws_size,
                              hipStream_t stream) {
  const float* x        = (const float*)d_in[0];
  const float* fwd_pad  = (const float*)d_in[1];
  const float* bwd_pad  = (const float*)d_in[2];
  const float* fwd_w    = (const float*)d_in[3];
  const float* bwd_w    = (const float*)d_in[4];
  const float* fwd_w1   = (const float*)d_in[5];
  const float* fwd_b1   = (const float*)d_in[6];
  const float* fwd_w2   = (const float*)d_in[7];
  const float* fwd_b2   = (const float*)d_in[8];
  const float* fwd_g    = (const float*)d_in[9];
  const float* fwd_beta = (const float*)d_in[10];
  const float* bwd_w1   = (const float*)d_in[11];
  const float* bwd_b1   = (const float*)d_in[12];
  const float* bwd_w2   = (const float*)d_in[13];
  const float* bwd_b2   = (const float*)d_in[14];
  const float* bwd_g    = (const float*)d_in[15];
  const float* bwd_beta = (const float*)d_in[16];
  float* out = (float*)d_out;

  const size_t WSZ = (size_t)D_DIM * D_DIM;           // 262144
  ushort_t* wt1 = (ushort_t*)d_ws;                    // [2][3][512][512] bf16
  ushort_t* wt2 = wt1 + 2 * NLAYER * WSZ;
  ushort_t* yln = wt2 + 2 * NLAYER * WSZ;             // [2][M][512] bf16
  ushort_t* h   = yln + (size_t)2 * M_ROWS * D_DIM;   // [2][M][512] bf16

  wprep_kernel<<<dim3(16, 16, 12), dim3(32, 8), 0, stream>>>(
      fwd_w1, fwd_w2, bwd_w1, bwd_w2, wt1, wt2);

  for (int l = 0; l < NLAYER; ++l) {
    const float *srcF, *srcB;
    int str;
    if (l == 0) {
      srcF = x; srcB = x; str = 512;
    } else {
      srcF = out + (size_t)(l - 1) * M_ROWS * 1024;
      srcB = srcF + 512;
      str = 1024;
    }
    const float* pLo = fwd_pad + (size_t)l * 3 * D_DIM;
    const float* pHi = bwd_pad + (size_t)l * 3 * D_DIM;

    conv_ln_kernel<<<dim3(M_ROWS / 16, 2), 256, 0, stream>>>(
        srcF, str, srcB, str, pLo, pHi,
        fwd_w + l * 4, bwd_w + l * 4,
        fwd_g + l * D_DIM, fwd_beta + l * D_DIM,
        bwd_g + l * D_DIM, bwd_beta + l * D_DIM,
        yln);

    gemmN_kernel<1><<<256, 512, 0, stream>>>(
        yln, wt1 + (size_t)l * WSZ, wt1 + (size_t)(NLAYER + l) * WSZ,
        fwd_b1 + l * D_DIM, bwd_b1 + l * D_DIM,
        h, nullptr,
        nullptr, nullptr, 0, nullptr, nullptr, nullptr, nullptr);

    gemmN_kernel<2><<<256, 512, 0, stream>>>(
        h, wt2 + (size_t)l * WSZ, wt2 + (size_t)(NLAYER + l) * WSZ,
        fwd_b2 + l * D_DIM, bwd_b2 + l * D_DIM,
        nullptr, out + (size_t)l * M_ROWS * 1024,
        srcF, srcB, str, pLo, pHi,
        fwd_w + l * 4, bwd_w + l * 4);
  }
}